// Round 1
// baseline (7947.195 us; speedup 1.0000x reference)
//
#include <hip/hip_runtime.h>
#include <math.h>

// Problem constants (from reference)
#define NB 16
#define NT 2048
#define ND 512
#define NK 8192
#define NN (NB*NT)      // 32768 rows
#define NTOP 8
#define SCALE_SIM 0.044194173824159216f   // 1/sqrt(512)

// Tiling
#define TM 64           // rows per workgroup
#define TN 128          // codes per tile
#define KC 32           // D-chunk staged in LDS
#define QS_LD 68        // padded leading dims (keep 16B alignment, reduce bank conflicts)
#define CS_LD 132
#define SIM_LD 132

// ---------------- zero-fill weights region ----------------
__global__ void zero_w_kernel(float4* __restrict__ w, int n4) {
  int i = blockIdx.x * blockDim.x + threadIdx.x;
  int stride = gridDim.x * blockDim.x;
  float4 z = make_float4(0.f, 0.f, 0.f, 0.f);
  for (; i < n4; i += stride) w[i] = z;
}

// ---------------- row norms: qq[NN], cc[NK] ----------------
__global__ void norms_kernel(const float* __restrict__ q,
                             const float* __restrict__ cbbase,
                             const int* __restrict__ modality,
                             float* __restrict__ qq, float* __restrict__ cc) {
  int w = (blockIdx.x * blockDim.x + threadIdx.x) >> 6;   // one wave per row
  int lane = threadIdx.x & 63;
  const float* src;
  float* dst;
  if (w < NN) {
    src = q + (size_t)w * ND;
    dst = qq + w;
  } else {
    const float* cb = cbbase + (size_t)(*modality) * ((size_t)NK * ND);
    int r = w - NN;
    src = cb + (size_t)r * ND;
    dst = cc + r;
  }
  const float4* s4 = (const float4*)src;
  float a = 0.f;
#pragma unroll
  for (int i = 0; i < ND / 4 / 64; ++i) {   // 2 iterations
    float4 v = s4[lane + i * 64];
    a = fmaf(v.x, v.x, fmaf(v.y, v.y, fmaf(v.z, v.z, fmaf(v.w, v.w, a))));
  }
#pragma unroll
  for (int off = 32; off > 0; off >>= 1) a += __shfl_down(a, off);
  if (lane == 0) *dst = a;
}

// ---------------- per-thread top-8 (sorted desc, ties -> lower index) ----------------
__device__ __forceinline__ void topk_insert(float tv[8], int ti[8], float v, int idx) {
  if (v > tv[7] || (v == tv[7] && idx < ti[7])) {
    tv[7] = v; ti[7] = idx;
#pragma unroll
    for (int j = 7; j > 0; --j) {
      bool sw = (tv[j] > tv[j - 1]) || (tv[j] == tv[j - 1] && ti[j] < ti[j - 1]);
      if (sw) {
        float fv = tv[j]; tv[j] = tv[j - 1]; tv[j - 1] = fv;
        int fi = ti[j]; ti[j] = ti[j - 1]; ti[j - 1] = fi;
      }
    }
  }
}

// ---------------- fused: fp32 GEMM sim + top-8 + softmax + outputs ----------------
__global__ __launch_bounds__(256, 2)
void vc_main_kernel(const float* __restrict__ q,
                    const float* __restrict__ comp,
                    const float* __restrict__ cbbase,
                    const float* __restrict__ logtemp,
                    const int* __restrict__ modality,
                    const float* __restrict__ qq,
                    const float* __restrict__ cc,
                    float* __restrict__ out_r,
                    float* __restrict__ out_w) {
  __shared__ union SM {
    struct { float Qs[KC][QS_LD]; float Cs[KC][CS_LD]; } st;  // 25.6 KB
    float sim[TM][SIM_LD];                                    // 33.8 KB
    struct { float mv[TM][4][8]; int mi[TM][4][8]; } mg;      // 16 KB
  } sm;
  __shared__ float wv[TM][NTOP];
  __shared__ int   wi[TM][NTOP];

  const float* cb = cbbase + (size_t)(*modality) * ((size_t)NK * ND);
  const int n0 = blockIdx.x * TM;
  const int t = threadIdx.x;
  const int tx = t & 15;   // row group: rows tx*4 .. tx*4+3
  const int ty = t >> 4;   // col group: cols ty*4..+3 and 64+ty*4..+3

  // top-k scan mapping: 4 threads per row
  const int srow = t >> 2;  // 0..63
  const int sh = t & 3;     // 0..3 -> cols [sh*32, sh*32+32)
  const float qq_r = qq[n0 + srow];

  float tv[8]; int ti[8];
#pragma unroll
  for (int j = 0; j < 8; ++j) { tv[j] = -INFINITY; ti[j] = 0x7fffffff; }

  for (int kt = 0; kt < NK / TN; ++kt) {
    const int c0 = kt * TN;
    float acc[4][8];
#pragma unroll
    for (int i = 0; i < 4; ++i)
#pragma unroll
      for (int j = 0; j < 8; ++j) acc[i][j] = 0.f;

    for (int dc = 0; dc < ND / KC; ++dc) {
      __syncthreads();  // prior LDS readers done (prev chunk / prev sim scan)
      // Q tile: 64 rows x 32 d = 512 float4, 2 per thread, stored transposed
#pragma unroll
      for (int li = 0; li < 2; ++li) {
        int l = t + li * 256;
        int r = l >> 3, c4 = l & 7;
        float4 v = *(const float4*)&q[(size_t)(n0 + r) * ND + dc * KC + c4 * 4];
        sm.st.Qs[c4 * 4 + 0][r] = v.x;
        sm.st.Qs[c4 * 4 + 1][r] = v.y;
        sm.st.Qs[c4 * 4 + 2][r] = v.z;
        sm.st.Qs[c4 * 4 + 3][r] = v.w;
      }
      // C tile: 128 codes x 32 d = 1024 float4, 4 per thread, transposed
#pragma unroll
      for (int li = 0; li < 4; ++li) {
        int l = t + li * 256;
        int r = l >> 3, c4 = l & 7;
        float4 v = *(const float4*)&cb[(size_t)(c0 + r) * ND + dc * KC + c4 * 4];
        sm.st.Cs[c4 * 4 + 0][r] = v.x;
        sm.st.Cs[c4 * 4 + 1][r] = v.y;
        sm.st.Cs[c4 * 4 + 2][r] = v.z;
        sm.st.Cs[c4 * 4 + 3][r] = v.w;
      }
      __syncthreads();
#pragma unroll
      for (int k = 0; k < KC; ++k) {
        float4 av = *(const float4*)&sm.st.Qs[k][tx * 4];
        float4 b0 = *(const float4*)&sm.st.Cs[k][ty * 4];
        float4 b1 = *(const float4*)&sm.st.Cs[k][64 + ty * 4];
        float a[4] = {av.x, av.y, av.z, av.w};
        float b[8] = {b0.x, b0.y, b0.z, b0.w, b1.x, b1.y, b1.z, b1.w};
#pragma unroll
        for (int i = 0; i < 4; ++i)
#pragma unroll
          for (int j = 0; j < 8; ++j) acc[i][j] = fmaf(a[i], b[j], acc[i][j]);
      }
    }
    __syncthreads();  // last chunk's LDS reads done before overwriting with sim
#pragma unroll
    for (int i = 0; i < 4; ++i) {
      *(float4*)&sm.sim[tx * 4 + i][ty * 4] =
          make_float4(acc[i][0], acc[i][1], acc[i][2], acc[i][3]);
      *(float4*)&sm.sim[tx * 4 + i][64 + ty * 4] =
          make_float4(acc[i][4], acc[i][5], acc[i][6], acc[i][7]);
    }
    __syncthreads();
    // scan this tile's 128 sims per row; 4 threads/row x 32 each
#pragma unroll 8
    for (int j = 0; j < 32; ++j) {
      int col = sh * 32 + j;
      float qc = sm.sim[srow][col];
      float v = fmaf(2.f, qc, -(qq_r + cc[c0 + col])) * SCALE_SIM;
      topk_insert(tv, ti, v, c0 + col);
    }
  }

  // merge 4 partial top-8 lists per row
  __syncthreads();
#pragma unroll
  for (int j = 0; j < 8; ++j) { sm.mg.mv[srow][sh][j] = tv[j]; sm.mg.mi[srow][sh][j] = ti[j]; }
  __syncthreads();
  if (sh == 0) {
#pragma unroll
    for (int h = 1; h < 4; ++h)
#pragma unroll
      for (int j = 0; j < 8; ++j)
        topk_insert(tv, ti, sm.mg.mv[srow][h][j], sm.mg.mi[srow][h][j]);
    // softmax with adaptive temperature
    int b = (n0 + srow) >> 11;  // row / T
    float at = expf(*logtemp) * (2.f - comp[b]);
    float m = tv[0];
    float e[8]; float s = 0.f;
#pragma unroll
    for (int j = 0; j < 8; ++j) { e[j] = expf((tv[j] - m) / at); s += e[j]; }
    float inv = 1.f / s;
#pragma unroll
    for (int j = 0; j < 8; ++j) { wv[srow][j] = e[j] * inv; wi[srow][j] = ti[j]; }
  }
  __syncthreads();

  // scatter weights (region pre-zeroed by zero_w_kernel)
  for (int s = t; s < TM * NTOP; s += 256) {
    int r = s >> 3, j = s & 7;
    out_w[(size_t)(n0 + r) * NK + wi[r][j]] = wv[r][j];
  }

  // retrieved = sum_j w_j * cb[idx_j]; 64 rows x 128 float4
  const float4* cb4 = (const float4*)cb;
  float4* or4 = (float4*)out_r;
  for (int s = t; s < TM * (ND / 4); s += 256) {
    int r = s >> 7, d4 = s & 127;
    float4 a = make_float4(0.f, 0.f, 0.f, 0.f);
#pragma unroll
    for (int j = 0; j < 8; ++j) {
      float w = wv[r][j];
      float4 c = cb4[(size_t)wi[r][j] * (ND / 4) + d4];
      a.x = fmaf(w, c.x, a.x);
      a.y = fmaf(w, c.y, a.y);
      a.z = fmaf(w, c.z, a.z);
      a.w = fmaf(w, c.w, a.w);
    }
    or4[(size_t)(n0 + r) * (ND / 4) + d4] = a;
  }
}

extern "C" void kernel_launch(void* const* d_in, const int* in_sizes, int n_in,
                              void* d_out, int out_size, void* d_ws, size_t ws_size,
                              hipStream_t stream) {
  (void)in_sizes; (void)n_in; (void)out_size; (void)ws_size;
  const float* q       = (const float*)d_in[0];
  const float* comp    = (const float*)d_in[1];
  const float* cbbase  = (const float*)d_in[2];
  const float* logtemp = (const float*)d_in[3];
  const int*   modality= (const int*)d_in[4];
  // d_in[5] = top_k (== 8, compile-time constant here)

  float* out_r = (float*)d_out;
  float* out_w = out_r + (size_t)NN * ND;

  float* qq = (float*)d_ws;
  float* cc = qq + NN;

  // 1) zero the 1.07 GB weights region (harness poisons it with 0xAA)
  zero_w_kernel<<<dim3(8192), dim3(256), 0, stream>>>((float4*)out_w, NN * (NK / 4));
  // 2) row norms for query and selected codebook
  norms_kernel<<<dim3((NN + NK) / 4), dim3(256), 0, stream>>>(q, cbbase, modality, qq, cc);
  // 3) fused sim + top-8 + softmax + outputs
  vc_main_kernel<<<dim3(NN / TM), dim3(256), 0, stream>>>(
      q, comp, cbbase, logtemp, modality, qq, cc, out_r, out_w);
}

// Round 3
// 2989.856 us; speedup vs baseline: 2.6581x; 2.6581x over previous
//
#include <hip/hip_runtime.h>
#include <math.h>

// Problem constants
#define NB 16
#define NT 2048
#define ND 512
#define NK 8192
#define NN (NB*NT)      // 32768 rows
#define NTOP 8
#define SCALE_SIM 0.044194173824159216f   // 1/sqrt(512)

// K2 tiling
#define CHUNK 2048      // cols per workgroup (4 chunks cover NK)
#define CT 128          // col tile
#define BK 32           // k-step

typedef __attribute__((ext_vector_type(8))) short bf16x8;   // 8 bf16 = 4 VGPR
typedef __attribute__((ext_vector_type(4))) float f32x4;    // MFMA acc / native float4

union H16 { unsigned short u; _Float16 h; };

// fp32 -> bf16 round-to-nearest-even
__device__ __forceinline__ unsigned int f2bf(float f) {
  unsigned int u = __float_as_uint(f);
  return (u + 0x7FFFu + ((u >> 16) & 1u)) >> 16;
}

// async global->LDS, 16B per lane; lds dst = wave-uniform base + lane*16
__device__ __forceinline__ void gl16(const void* g, void* l) {
  __builtin_amdgcn_global_load_lds((const __attribute__((address_space(1))) void*)g,
                                   (__attribute__((address_space(3))) void*)l, 16, 0, 0);
}

// sorted-desc insert (approx stage: value-only, ties arbitrary)
template <int NL>
__device__ __forceinline__ void tinsert(float* tv, int* ti, float v, int idx) {
  if (v > tv[NL - 1]) {
    tv[NL - 1] = v; ti[NL - 1] = idx;
#pragma unroll
    for (int j = NL - 1; j > 0; --j) {
      if (tv[j] > tv[j - 1]) {
        float fv = tv[j]; tv[j] = tv[j - 1]; tv[j - 1] = fv;
        int fi = ti[j]; ti[j] = ti[j - 1]; ti[j - 1] = fi;
      }
    }
  }
}

// ---------------- K1: bf16 conversion + ||c||^2 ----------------
// one wave per row; rows [0,NN) = q, rows [NN,NN+NK) = selected codebook
__global__ void prep_kernel(const float* __restrict__ q,
                            const float* __restrict__ cbbase,
                            const int* __restrict__ modality,
                            ushort* __restrict__ q_bf, ushort* __restrict__ cb_bf,
                            float* __restrict__ cc) {
  int gw = (blockIdx.x * blockDim.x + threadIdx.x) >> 6;
  int lane = threadIdx.x & 63;
  if (gw < NN) {
    const float* src = q + (size_t)gw * ND + lane * 8;
    float4 v0 = ((const float4*)src)[0];
    float4 v1 = ((const float4*)src)[1];
    uint4 o;
    o.x = f2bf(v0.x) | (f2bf(v0.y) << 16);
    o.y = f2bf(v0.z) | (f2bf(v0.w) << 16);
    o.z = f2bf(v1.x) | (f2bf(v1.y) << 16);
    o.w = f2bf(v1.z) | (f2bf(v1.w) << 16);
    *(uint4*)(q_bf + (size_t)gw * ND + lane * 8) = o;
  } else {
    int r = gw - NN;
    const float* cb = cbbase + (size_t)(*modality) * ((size_t)NK * ND);
    const float* src = cb + (size_t)r * ND + lane * 8;
    float4 v0 = ((const float4*)src)[0];
    float4 v1 = ((const float4*)src)[1];
    uint4 o;
    o.x = f2bf(v0.x) | (f2bf(v0.y) << 16);
    o.y = f2bf(v0.z) | (f2bf(v0.w) << 16);
    o.z = f2bf(v1.x) | (f2bf(v1.y) << 16);
    o.w = f2bf(v1.z) | (f2bf(v1.w) << 16);
    *(uint4*)(cb_bf + (size_t)r * ND + lane * 8) = o;
    float s = 0.f;
    s = fmaf(v0.x, v0.x, s); s = fmaf(v0.y, v0.y, s);
    s = fmaf(v0.z, v0.z, s); s = fmaf(v0.w, v0.w, s);
    s = fmaf(v1.x, v1.x, s); s = fmaf(v1.y, v1.y, s);
    s = fmaf(v1.z, v1.z, s); s = fmaf(v1.w, v1.w, s);
#pragma unroll
    for (int off = 32; off > 0; off >>= 1) s += __shfl_down(s, off);
    if (lane == 0) cc[r] = s;
  }
}

// ---------------- K2: bf16 MFMA sim + per-chunk top-16 + fused zero ----------------
// grid 1024 = 256 row-blocks x 4 col-chunks; 256 threads = 4 waves, wave tile 64x64
__global__ __launch_bounds__(256, 2)
void sim_topk_kernel(const ushort* __restrict__ q_bf, const ushort* __restrict__ cb_bf,
                     const float* __restrict__ cc, float* __restrict__ out_w,
                     float* __restrict__ cand_val, int* __restrict__ cand_idx) {
  __shared__ ushort A_lds[128 * 32];     // [row][k] bf16, 8 KB, matches gl16 lane order
  __shared__ ushort B_lds[128 * 32];     // [col][k] bf16, 8 KB
  __shared__ ushort K_lds[128 * 132];    // fp16 keys [col][row], 33 KB; aliased by merge

  const int rb = blockIdx.x >> 2, ch = blockIdx.x & 3;
  const int r0 = rb * 128, ccol0 = ch * CHUNK;
  const int t = threadIdx.x, lane = t & 63, w = t >> 6;
  const int wr = w >> 1, wc = w & 1;           // wave quadrant in 128x128 tile
  const int m = lane & 15, quad = lane >> 4;   // MFMA lane decomposition
  const int srow = t >> 1, sh = t & 1;         // scan: 2 threads/row, 64 cols each

  // staging addresses (wave w stages rows/cols w*32..w*32+32; 2 instrs of 16 each)
  const ushort* gA = q_bf + (size_t)(r0 + w * 32 + (lane >> 2)) * ND + (lane & 3) * 8;
  const ushort* gB = cb_bf + (size_t)(ccol0 + w * 32 + (lane >> 2)) * ND + (lane & 3) * 8;
  ushort* lA = &A_lds[w * 1024];
  ushort* lB = &B_lds[w * 1024];

  const int aoff = (wr * 64 + m) * 32 + quad * 8;   // + i*512 per row-frag
  const int boff = (wc * 64 + m) * 32 + quad * 8;   // + j*512 per col-frag

  float tv[16]; int ti[16];
#pragma unroll
  for (int j = 0; j < 16; ++j) { tv[j] = -INFINITY; ti[j] = 0; }

  const f32x4 z4 = (f32x4){0.f, 0.f, 0.f, 0.f};

  for (int tile = 0; tile < 16; ++tile) {
    const int c0 = ccol0 + tile * CT;
    const ushort* gBt = gB + (size_t)tile * CT * ND;

    f32x4 acc[4][4];
#pragma unroll
    for (int i = 0; i < 4; ++i)
#pragma unroll
      for (int j = 0; j < 4; ++j) acc[i][j] = (f32x4){0.f, 0.f, 0.f, 0.f};

#pragma unroll
    for (int s = 0; s < ND / BK; ++s) {        // 16 k-steps
      __syncthreads();                          // prev readers done
      gl16(gA + s * 32, lA);
      gl16(gA + s * 32 + 16 * ND, lA + 512);
      gl16(gBt + s * 32, lB);
      gl16(gBt + s * 32 + 16 * ND, lB + 512);
      __syncthreads();                          // loads visible (vmcnt drain)
      bf16x8 a[4], b[4];
#pragma unroll
      for (int i = 0; i < 4; ++i) a[i] = *(const bf16x8*)&A_lds[aoff + i * 512];
#pragma unroll
      for (int j = 0; j < 4; ++j) b[j] = *(const bf16x8*)&B_lds[boff + j * 512];
#pragma unroll
      for (int i = 0; i < 4; ++i)
#pragma unroll
        for (int j = 0; j < 4; ++j)
          acc[i][j] = __builtin_amdgcn_mfma_f32_16x16x32_bf16(a[i], b[j], acc[i][j], 0, 0, 0);
    }

    // dump fp16 keys: key = 2*dot - cc + 512 (centered; qq cancels in per-row ranking)
    // C/D layout: col = lane&15, row = quad*4 + reg
    __syncthreads();
#pragma unroll
    for (int j = 0; j < 4; ++j) {
      int col_l = wc * 64 + j * 16 + m;
      float nb = 512.0f - cc[c0 + col_l];
#pragma unroll
      for (int i = 0; i < 4; ++i) {
        H16 h0, h1, h2, h3;
        h0.h = (_Float16)fmaf(2.f, acc[i][j][0], nb);
        h1.h = (_Float16)fmaf(2.f, acc[i][j][1], nb);
        h2.h = (_Float16)fmaf(2.f, acc[i][j][2], nb);
        h3.h = (_Float16)fmaf(2.f, acc[i][j][3], nb);
        uint2 p;
        p.x = (unsigned)h0.u | ((unsigned)h1.u << 16);
        p.y = (unsigned)h2.u | ((unsigned)h3.u << 16);
        *(uint2*)&K_lds[col_l * 132 + wr * 64 + i * 16 + quad * 4] = p;
      }
    }
    __syncthreads();

    // fused zero of this wg's out_w slab: 8 rows x 2048 cols per tile (drains in scan shadow)
    {
      f32x4* zp = (f32x4*)(out_w + (size_t)(r0 + tile * 8 + (t >> 5)) * NK +
                           ccol0 + (t & 31) * 64);
#pragma unroll
      for (int ii = 0; ii < 16; ++ii) __builtin_nontemporal_store(z4, zp + ii);
    }

    // scan 64 cols for this thread's row
#pragma unroll 8
    for (int j = 0; j < 64; ++j) {
      int cl = sh * 64 + j;
      H16 hh; hh.u = K_lds[cl * 132 + srow];
      tinsert<16>(tv, ti, (float)hh.h, c0 + cl);
    }
  }

  // merge thread-pair lists -> per-row per-chunk top-16 in ws
  __syncthreads();
  float* mgv = (float*)K_lds;                 // [128][32]
  int* mgi = (int*)(K_lds + 8192);            // byte offset 16384
#pragma unroll
  for (int j = 0; j < 16; ++j) { mgv[srow * 32 + sh * 16 + j] = tv[j]; mgi[srow * 32 + sh * 16 + j] = ti[j]; }
  __syncthreads();
  if (sh == 0) {
#pragma unroll
    for (int j = 0; j < 16; ++j)
      tinsert<16>(tv, ti, mgv[srow * 32 + 16 + j], mgi[srow * 32 + 16 + j]);
    size_t base = (size_t)(r0 + srow) * 64 + ch * 16;
#pragma unroll
    for (int j = 0; j < 16; ++j) { cand_val[base + j] = tv[j]; cand_idx[base + j] = ti[j]; }
  }
}

// ---------------- K3: merge, exact fp32 re-score top-12, top-8 softmax, outputs ----------------
__global__ __launch_bounds__(256, 4)
void finalize_kernel(const float* __restrict__ q, const float* __restrict__ comp,
                     const float* __restrict__ cbbase, const float* __restrict__ logtemp,
                     const int* __restrict__ modality, const float* __restrict__ cc,
                     const float* __restrict__ cand_val, const int* __restrict__ cand_idx,
                     float* __restrict__ out_r, float* __restrict__ out_w) {
  __shared__ int ssel[4][12];
  const int w = threadIdx.x >> 6, lane = threadIdx.x & 63;
  const int r = blockIdx.x * 4 + w;
  const float* cb = cbbase + (size_t)(*modality) * ((size_t)NK * ND);

  // approx top-12 of 64 candidates (ranks unique: strict order w/ index tie-break)
  float v = cand_val[(size_t)r * 64 + lane];
  int ci = cand_idx[(size_t)r * 64 + lane];
  int rank = 0;
  for (int j = 0; j < 64; ++j) {
    float vj = __uint_as_float(__builtin_amdgcn_readlane(__float_as_uint(v), j));
    int ij = (int)__builtin_amdgcn_readlane((unsigned)ci, j);
    rank += (vj > v || (vj == v && ij < ci)) ? 1 : 0;
  }
  if (rank < 12) ssel[w][rank] = ci;
  __syncthreads();

  // exact fp32 re-score: 4 lanes per candidate, 128 dims each
  const int c = lane >> 2, part = lane & 3;
  const int cidx = ssel[w][c < 12 ? c : 11];
  float dot = 0.f;
  {
    const float4* qv = (const float4*)(q + (size_t)r * ND) + part * 32;
    const float4* cv = (const float4*)(cb + (size_t)cidx * ND) + part * 32;
#pragma unroll 8
    for (int i = 0; i < 32; ++i) {
      float4 a = qv[i], b = cv[i];
      dot = fmaf(a.x, b.x, dot); dot = fmaf(a.y, b.y, dot);
      dot = fmaf(a.z, b.z, dot); dot = fmaf(a.w, b.w, dot);
    }
  }
  dot += __shfl_xor(dot, 1);
  dot += __shfl_xor(dot, 2);
  float key = fmaf(2.f, dot, -cc[cidx]);   // sim*sqrt(d) + qq  (qq cancels in softmax)

  // broadcast 12 (key, idx) to all lanes
  float k12[12]; int i12[12];
#pragma unroll
  for (int j = 0; j < 12; ++j) {
    k12[j] = __shfl(key, j * 4);
    i12[j] = __shfl(cidx, j * 4);
  }
  // exact rank among 12 (tie -> lower index, matching lax.top_k)
  int rk = 0;
#pragma unroll
  for (int j = 0; j < 12; ++j)
    rk += (k12[j] > key || (k12[j] == key && i12[j] < cidx)) ? 1 : 0;
  bool sel = (part == 0) && (c < 12) && (rk < NTOP);

  // softmax over the exact top-8
  float at = __expf(*logtemp) * (2.f - comp[r >> 11]);
  float mx = -INFINITY;
#pragma unroll
  for (int j = 0; j < 12; ++j) mx = fmaxf(mx, k12[j]);
  float e = sel ? __expf((key - mx) * (SCALE_SIM / at)) : 0.f;
  float es = e;
#pragma unroll
  for (int off = 32; off > 0; off >>= 1) es += __shfl_xor(es, off);
  float wgt = e / es;
  if (sel) out_w[(size_t)r * NK + cidx] = wgt;   // slab pre-zeroed by K2

  // retrieved = sum_j w_j * cb[idx_j]; non-selected have w==0 exactly
  float w12[12];
#pragma unroll
  for (int j = 0; j < 12; ++j) w12[j] = __shfl(wgt, j * 4);
  float4 a0 = make_float4(0.f, 0.f, 0.f, 0.f), a1 = a0;
  const float4* cb4 = (const float4*)cb;
#pragma unroll
  for (int j = 0; j < 12; ++j) {
    const float4* cp = cb4 + (size_t)i12[j] * (ND / 4) + lane * 2;
    float ww = w12[j];
    float4 c0v = cp[0], c1v = cp[1];
    a0.x = fmaf(ww, c0v.x, a0.x); a0.y = fmaf(ww, c0v.y, a0.y);
    a0.z = fmaf(ww, c0v.z, a0.z); a0.w = fmaf(ww, c0v.w, a0.w);
    a1.x = fmaf(ww, c1v.x, a1.x); a1.y = fmaf(ww, c1v.y, a1.y);
    a1.z = fmaf(ww, c1v.z, a1.z); a1.w = fmaf(ww, c1v.w, a1.w);
  }
  float4* orp = (float4*)(out_r + (size_t)r * ND) + lane * 2;
  orp[0] = a0; orp[1] = a1;
}

extern "C" void kernel_launch(void* const* d_in, const int* in_sizes, int n_in,
                              void* d_out, int out_size, void* d_ws, size_t ws_size,
                              hipStream_t stream) {
  (void)in_sizes; (void)n_in; (void)out_size; (void)ws_size;
  const float* q        = (const float*)d_in[0];
  const float* comp     = (const float*)d_in[1];
  const float* cbbase   = (const float*)d_in[2];
  const float* logtemp  = (const float*)d_in[3];
  const int*   modality = (const int*)d_in[4];
  // d_in[5] = top_k (== 8, compile-time)

  float* out_r = (float*)d_out;
  float* out_w = out_r + (size_t)NN * ND;

  // workspace layout (~58.8 MB)
  ushort* q_bf   = (ushort*)d_ws;                          // 33,554,432 B
  ushort* cb_bf  = q_bf + (size_t)NN * ND;                 //  8,388,608 B
  float*  ccw    = (float*)(cb_bf + (size_t)NK * ND);      //     32,768 B
  float*  c_val  = ccw + NK;                               //  8,388,608 B
  int*    c_idx  = (int*)(c_val + (size_t)NN * 64);        //  8,388,608 B

  prep_kernel<<<dim3((NN + NK) / 4), dim3(256), 0, stream>>>(q, cbbase, modality, q_bf, cb_bf, ccw);
  sim_topk_kernel<<<dim3((NN / 128) * 4), dim3(256), 0, stream>>>(q_bf, cb_bf, ccw, out_w, c_val, c_idx);
  finalize_kernel<<<dim3(NN / 4), dim3(256), 0, stream>>>(q, comp, cbbase, logtemp, modality, ccw,
                                                          c_val, c_idx, out_r, out_w);
}

// Round 4
// 2781.039 us; speedup vs baseline: 2.8576x; 1.0751x over previous
//
#include <hip/hip_runtime.h>
#include <math.h>

// Problem constants
#define NB 16
#define NT 2048
#define ND 512
#define NK 8192
#define NN (NB*NT)      // 32768 rows
#define NTOP 8
#define SCALE_SIM 0.044194173824159216f   // 1/sqrt(512)

// K2 tiling
#define CHUNK 2048      // cols per workgroup (4 chunks cover NK)
#define CT 128          // col tile
#define BK 32           // k-step

typedef __attribute__((ext_vector_type(8))) short bf16x8;   // 8 bf16 = 4 VGPR
typedef __attribute__((ext_vector_type(4))) float f32x4;    // MFMA acc / native float4

union H16 { unsigned short u; _Float16 h; };

// fp32 -> bf16 round-to-nearest-even
__device__ __forceinline__ unsigned int f2bf(float f) {
  unsigned int u = __float_as_uint(f);
  return (u + 0x7FFFu + ((u >> 16) & 1u)) >> 16;
}

// async global->LDS, 16B per lane; lds dst = wave-uniform base + lane*16
__device__ __forceinline__ void gl16(const void* g, void* l) {
  __builtin_amdgcn_global_load_lds((const __attribute__((address_space(1))) void*)g,
                                   (__attribute__((address_space(3))) void*)l, 16, 0, 0);
}

// sorted-desc insert (approx stage: value-only, ties arbitrary)
template <int NL>
__device__ __forceinline__ void tinsert(float* tv, int* ti, float v, int idx) {
  if (v > tv[NL - 1]) {
    tv[NL - 1] = v; ti[NL - 1] = idx;
#pragma unroll
    for (int j = NL - 1; j > 0; --j) {
      if (tv[j] > tv[j - 1]) {
        float fv = tv[j]; tv[j] = tv[j - 1]; tv[j - 1] = fv;
        int fi = ti[j]; ti[j] = ti[j - 1]; ti[j - 1] = fi;
      }
    }
  }
}

// ---------------- K1: bf16 conversion + ||c||^2 ----------------
__global__ void prep_kernel(const float* __restrict__ q,
                            const float* __restrict__ cbbase,
                            const int* __restrict__ modality,
                            ushort* __restrict__ q_bf, ushort* __restrict__ cb_bf,
                            float* __restrict__ cc) {
  int gw = (blockIdx.x * blockDim.x + threadIdx.x) >> 6;
  int lane = threadIdx.x & 63;
  if (gw < NN) {
    const float* src = q + (size_t)gw * ND + lane * 8;
    float4 v0 = ((const float4*)src)[0];
    float4 v1 = ((const float4*)src)[1];
    uint4 o;
    o.x = f2bf(v0.x) | (f2bf(v0.y) << 16);
    o.y = f2bf(v0.z) | (f2bf(v0.w) << 16);
    o.z = f2bf(v1.x) | (f2bf(v1.y) << 16);
    o.w = f2bf(v1.z) | (f2bf(v1.w) << 16);
    *(uint4*)(q_bf + (size_t)gw * ND + lane * 8) = o;
  } else {
    int r = gw - NN;
    const float* cb = cbbase + (size_t)(*modality) * ((size_t)NK * ND);
    const float* src = cb + (size_t)r * ND + lane * 8;
    float4 v0 = ((const float4*)src)[0];
    float4 v1 = ((const float4*)src)[1];
    uint4 o;
    o.x = f2bf(v0.x) | (f2bf(v0.y) << 16);
    o.y = f2bf(v0.z) | (f2bf(v0.w) << 16);
    o.z = f2bf(v1.x) | (f2bf(v1.y) << 16);
    o.w = f2bf(v1.z) | (f2bf(v1.w) << 16);
    *(uint4*)(cb_bf + (size_t)r * ND + lane * 8) = o;
    float s = 0.f;
    s = fmaf(v0.x, v0.x, s); s = fmaf(v0.y, v0.y, s);
    s = fmaf(v0.z, v0.z, s); s = fmaf(v0.w, v0.w, s);
    s = fmaf(v1.x, v1.x, s); s = fmaf(v1.y, v1.y, s);
    s = fmaf(v1.z, v1.z, s); s = fmaf(v1.w, v1.w, s);
#pragma unroll
    for (int off = 32; off > 0; off >>= 1) s += __shfl_down(s, off);
    if (lane == 0) cc[r] = s;
  }
}

// ---------------- K2: bf16 MFMA sim + per-chunk top-16 + fused coalesced zero ----------------
// grid 1024 = 256 row-blocks x 4 col-chunks; 256 threads = 4 waves, wave tile 64x64
// Double-buffered LDS staging: 1 barrier per k-step; next step's loads fly during MFMA.
__global__ __launch_bounds__(256, 2)
void sim_topk_kernel(const ushort* __restrict__ q_bf, const ushort* __restrict__ cb_bf,
                     const float* __restrict__ cc, float* __restrict__ out_w,
                     float* __restrict__ cand_val, int* __restrict__ cand_idx) {
  __shared__ ushort A_lds[2][128 * 32];  // [buf][row][k] bf16, 16 KB
  __shared__ ushort B_lds[2][128 * 32];  // [buf][col][k] bf16, 16 KB
  __shared__ ushort K_lds[128 * 132];    // fp16 keys [col][row], 33 KB; aliased by merge

  const int rb = blockIdx.x >> 2, ch = blockIdx.x & 3;
  const int r0 = rb * 128, ccol0 = ch * CHUNK;
  const int t = threadIdx.x, lane = t & 63, w = t >> 6;
  const int wr = w >> 1, wc = w & 1;           // wave quadrant in 128x128 tile
  const int m = lane & 15, quad = lane >> 4;   // MFMA lane decomposition
  const int srow = t >> 1, sh = t & 1;         // scan: 2 threads/row, 64 cols each

  // staging addresses (wave w stages rows/cols w*32..w*32+32; 2 instrs of 16B/lane each)
  const ushort* gA = q_bf + (size_t)(r0 + w * 32 + (lane >> 2)) * ND + (lane & 3) * 8;
  const ushort* gB = cb_bf + (size_t)(ccol0 + w * 32 + (lane >> 2)) * ND + (lane & 3) * 8;

  const int aoff = (wr * 64 + m) * 32 + quad * 8;   // + i*512 per row-frag
  const int boff = (wc * 64 + m) * 32 + quad * 8;   // + j*512 per col-frag

  float tv[16]; int ti[16];
#pragma unroll
  for (int j = 0; j < 16; ++j) { tv[j] = -INFINITY; ti[j] = 0; }

  const f32x4 z4 = (f32x4){0.f, 0.f, 0.f, 0.f};

  // prologue: stage (tile=0, s=0) into buffer 0
  {
    ushort* lA = &A_lds[0][w * 1024];
    ushort* lB = &B_lds[0][w * 1024];
    gl16(gA, lA);
    gl16(gA + 16 * ND, lA + 512);
    gl16(gB, lB);
    gl16(gB + 16 * ND, lB + 512);
  }

  for (int tile = 0; tile < 16; ++tile) {
    f32x4 acc[4][4];
#pragma unroll
    for (int i = 0; i < 4; ++i)
#pragma unroll
      for (int j = 0; j < 4; ++j) acc[i][j] = (f32x4){0.f, 0.f, 0.f, 0.f};

#pragma unroll
    for (int s = 0; s < ND / BK; ++s) {        // 16 k-steps
      __syncthreads();                          // buf[s&1] staged & visible (vmcnt drain)
      // prefetch next k-step (or next tile's step 0) into the other buffer
      {
        int ntile = (s < 15) ? tile : tile + 1;
        if (ntile < 16) {
          int ns = (s + 1) & 15;
          int nb = (s + 1) & 1;
          ushort* lA = &A_lds[nb][w * 1024];
          ushort* lB = &B_lds[nb][w * 1024];
          const ushort* gBt = gB + (size_t)ntile * CT * ND;
          gl16(gA + ns * 32, lA);
          gl16(gA + ns * 32 + 16 * ND, lA + 512);
          gl16(gBt + ns * 32, lB);
          gl16(gBt + ns * 32 + 16 * ND, lB + 512);
        }
      }
      const ushort* Ab = &A_lds[s & 1][0];
      const ushort* Bb = &B_lds[s & 1][0];
      bf16x8 a[4], b[4];
#pragma unroll
      for (int i = 0; i < 4; ++i) a[i] = *(const bf16x8*)&Ab[aoff + i * 512];
#pragma unroll
      for (int j = 0; j < 4; ++j) b[j] = *(const bf16x8*)&Bb[boff + j * 512];
#pragma unroll
      for (int i = 0; i < 4; ++i)
#pragma unroll
        for (int j = 0; j < 4; ++j)
          acc[i][j] = __builtin_amdgcn_mfma_f32_16x16x32_bf16(a[i], b[j], acc[i][j], 0, 0, 0);
    }

    const int c0 = ccol0 + tile * CT;
    // dump fp16 keys: key = 2*dot - cc + 512 (centered; qq cancels in per-row ranking)
    // C/D layout: col = lane&15, row = quad*4 + reg
#pragma unroll
    for (int j = 0; j < 4; ++j) {
      int col_l = wc * 64 + j * 16 + m;
      float nb = 512.0f - cc[c0 + col_l];
#pragma unroll
      for (int i = 0; i < 4; ++i) {
        H16 h0, h1, h2, h3;
        h0.h = (_Float16)fmaf(2.f, acc[i][j][0], nb);
        h1.h = (_Float16)fmaf(2.f, acc[i][j][1], nb);
        h2.h = (_Float16)fmaf(2.f, acc[i][j][2], nb);
        h3.h = (_Float16)fmaf(2.f, acc[i][j][3], nb);
        uint2 p;
        p.x = (unsigned)h0.u | ((unsigned)h1.u << 16);
        p.y = (unsigned)h2.u | ((unsigned)h3.u << 16);
        *(uint2*)&K_lds[col_l * 132 + wr * 64 + i * 16 + quad * 4] = p;
      }
    }
    __syncthreads();

    // fused zero of this wg's out_w slab: 8 rows x 2048 cols per tile, COALESCED:
    // consecutive lanes -> consecutive float4 (1 KB contiguous per wave-instruction)
    {
      size_t rowbase = (size_t)(r0 + tile * 8) * NK + ccol0;
#pragma unroll
      for (int ii = 0; ii < 16; ++ii) {
        int s = ii * 256 + t;                   // 0..4095 over 8 rows x 512 float4
        f32x4* zp = (f32x4*)(out_w + rowbase + (size_t)(s >> 9) * NK + (size_t)(s & 511) * 4);
        __builtin_nontemporal_store(z4, zp);
      }
    }

    // scan 64 cols for this thread's row
#pragma unroll 8
    for (int j = 0; j < 64; ++j) {
      int cl = sh * 64 + j;
      H16 hh; hh.u = K_lds[cl * 132 + srow];
      tinsert<16>(tv, ti, (float)hh.h, c0 + cl);
    }
  }

  // merge thread-pair lists -> per-row per-chunk top-16 in ws
  __syncthreads();
  float* mgv = (float*)K_lds;                 // [128][32]
  int* mgi = (int*)(K_lds + 8192);            // byte offset 16384
#pragma unroll
  for (int j = 0; j < 16; ++j) { mgv[srow * 32 + sh * 16 + j] = tv[j]; mgi[srow * 32 + sh * 16 + j] = ti[j]; }
  __syncthreads();
  if (sh == 0) {
#pragma unroll
    for (int j = 0; j < 16; ++j)
      tinsert<16>(tv, ti, mgv[srow * 32 + 16 + j], mgi[srow * 32 + 16 + j]);
    size_t base = (size_t)(r0 + srow) * 64 + ch * 16;
#pragma unroll
    for (int j = 0; j < 16; ++j) { cand_val[base + j] = tv[j]; cand_idx[base + j] = ti[j]; }
  }
}

// ---------------- K3: merge, exact fp32 re-score top-12, top-8 softmax, outputs ----------------
__global__ __launch_bounds__(256, 4)
void finalize_kernel(const float* __restrict__ q, const float* __restrict__ comp,
                     const float* __restrict__ cbbase, const float* __restrict__ logtemp,
                     const int* __restrict__ modality, const float* __restrict__ cc,
                     const float* __restrict__ cand_val, const int* __restrict__ cand_idx,
                     float* __restrict__ out_r, float* __restrict__ out_w) {
  __shared__ int ssel[4][12];
  const int w = threadIdx.x >> 6, lane = threadIdx.x & 63;
  const int r = blockIdx.x * 4 + w;
  const float* cb = cbbase + (size_t)(*modality) * ((size_t)NK * ND);

  // approx top-12 of 64 candidates (ranks unique: strict order w/ index tie-break)
  float v = cand_val[(size_t)r * 64 + lane];
  int ci = cand_idx[(size_t)r * 64 + lane];
  int rank = 0;
  for (int j = 0; j < 64; ++j) {
    float vj = __uint_as_float(__builtin_amdgcn_readlane(__float_as_uint(v), j));
    int ij = (int)__builtin_amdgcn_readlane((unsigned)ci, j);
    rank += (vj > v || (vj == v && ij < ci)) ? 1 : 0;
  }
  if (rank < 12) ssel[w][rank] = ci;
  __syncthreads();

  // exact fp32 re-score: 4 lanes per candidate, 128 dims each
  const int c = lane >> 2, part = lane & 3;
  const int cidx = ssel[w][c < 12 ? c : 11];
  float dot = 0.f;
  {
    const float4* qv = (const float4*)(q + (size_t)r * ND) + part * 32;
    const float4* cv = (const float4*)(cb + (size_t)cidx * ND) + part * 32;
#pragma unroll 8
    for (int i = 0; i < 32; ++i) {
      float4 a = qv[i], b = cv[i];
      dot = fmaf(a.x, b.x, dot); dot = fmaf(a.y, b.y, dot);
      dot = fmaf(a.z, b.z, dot); dot = fmaf(a.w, b.w, dot);
    }
  }
  dot += __shfl_xor(dot, 1);
  dot += __shfl_xor(dot, 2);
  float key = fmaf(2.f, dot, -cc[cidx]);   // -dist^2 + qq (qq cancels in softmax)

  // broadcast 12 (key, idx) to all lanes
  float k12[12]; int i12[12];
#pragma unroll
  for (int j = 0; j < 12; ++j) {
    k12[j] = __shfl(key, j * 4);
    i12[j] = __shfl(cidx, j * 4);
  }
  // exact rank among 12 (tie -> lower index, matching lax.top_k)
  int rk = 0;
#pragma unroll
  for (int j = 0; j < 12; ++j)
    rk += (k12[j] > key || (k12[j] == key && i12[j] < cidx)) ? 1 : 0;
  bool sel = (part == 0) && (c < 12) && (rk < NTOP);

  // softmax over the exact top-8
  float at = __expf(*logtemp) * (2.f - comp[r >> 11]);
  float mx = -INFINITY;
#pragma unroll
  for (int j = 0; j < 12; ++j) mx = fmaxf(mx, k12[j]);
  float e = sel ? __expf((key - mx) * (SCALE_SIM / at)) : 0.f;
  float es = e;
#pragma unroll
  for (int off = 32; off > 0; off >>= 1) es += __shfl_xor(es, off);
  float wgt = e / es;
  if (sel) out_w[(size_t)r * NK + cidx] = wgt;   // slab pre-zeroed by K2

  // retrieved = sum_j w_j * cb[idx_j]; non-selected have w==0 exactly
  float w12[12];
#pragma unroll
  for (int j = 0; j < 12; ++j) w12[j] = __shfl(wgt, j * 4);
  float4 a0 = make_float4(0.f, 0.f, 0.f, 0.f), a1 = a0;
  const float4* cb4 = (const float4*)cb;
#pragma unroll
  for (int j = 0; j < 12; ++j) {
    const float4* cp = cb4 + (size_t)i12[j] * (ND / 4) + lane * 2;
    float ww = w12[j];
    float4 c0v = cp[0], c1v = cp[1];
    a0.x = fmaf(ww, c0v.x, a0.x); a0.y = fmaf(ww, c0v.y, a0.y);
    a0.z = fmaf(ww, c0v.z, a0.z); a0.w = fmaf(ww, c0v.w, a0.w);
    a1.x = fmaf(ww, c1v.x, a1.x); a1.y = fmaf(ww, c1v.y, a1.y);
    a1.z = fmaf(ww, c1v.z, a1.z); a1.w = fmaf(ww, c1v.w, a1.w);
  }
  float4* orp = (float4*)(out_r + (size_t)r * ND) + lane * 2;
  orp[0] = a0; orp[1] = a1;
}

extern "C" void kernel_launch(void* const* d_in, const int* in_sizes, int n_in,
                              void* d_out, int out_size, void* d_ws, size_t ws_size,
                              hipStream_t stream) {
  (void)in_sizes; (void)n_in; (void)out_size; (void)ws_size;
  const float* q        = (const float*)d_in[0];
  const float* comp     = (const float*)d_in[1];
  const float* cbbase   = (const float*)d_in[2];
  const float* logtemp  = (const float*)d_in[3];
  const int*   modality = (const int*)d_in[4];
  // d_in[5] = top_k (== 8, compile-time)

  float* out_r = (float*)d_out;
  float* out_w = out_r + (size_t)NN * ND;

  // workspace layout (~58.8 MB)
  ushort* q_bf   = (ushort*)d_ws;                          // 33,554,432 B
  ushort* cb_bf  = q_bf + (size_t)NN * ND;                 //  8,388,608 B
  float*  ccw    = (float*)(cb_bf + (size_t)NK * ND);      //     32,768 B
  float*  c_val  = ccw + NK;                               //  8,388,608 B
  int*    c_idx  = (int*)(c_val + (size_t)NN * 64);        //  8,388,608 B

  prep_kernel<<<dim3((NN + NK) / 4), dim3(256), 0, stream>>>(q, cbbase, modality, q_bf, cb_bf, ccw);
  sim_topk_kernel<<<dim3((NN / 128) * 4), dim3(256), 0, stream>>>(q_bf, cb_bf, ccw, out_w, c_val, c_idx);
  finalize_kernel<<<dim3(NN / 4), dim3(256), 0, stream>>>(q, comp, cbbase, logtemp, modality, ccw,
                                                          c_val, c_idx, out_r, out_w);
}